// Round 5
// baseline (298.665 us; speedup 1.0000x reference)
//
#include <hip/hip_runtime.h>

typedef unsigned short u16;
typedef __attribute__((ext_vector_type(8))) short s8b;       // 8 x bf16 bits
typedef __attribute__((ext_vector_type(4))) float f4;
typedef __attribute__((ext_vector_type(8))) _Float16 h8;     // 8 x f16

static __device__ __forceinline__ float b2f(u16 u){
  return __uint_as_float(((unsigned int)u) << 16);
}
static __device__ __forceinline__ u16 f2b(float f){
  unsigned int u = __float_as_uint(f);
  u = (u + 0x7FFFu + ((u >> 16) & 1u)) >> 16;   // RNE
  return (u16)u;
}
static __device__ __forceinline__ f4 mfma16(s8b a, s8b b, f4 c){
  return __builtin_amdgcn_mfma_f32_16x16x32_bf16(a, b, c, 0, 0, 0);
}
static __device__ __forceinline__ s8b load8(const float* p){
  float4 a = ((const float4*)p)[0];
  float4 b = ((const float4*)p)[1];
  s8b r;
  r[0] = (short)f2b(a.x); r[1] = (short)f2b(a.y);
  r[2] = (short)f2b(a.z); r[3] = (short)f2b(a.w);
  r[4] = (short)f2b(b.x); r[5] = (short)f2b(b.y);
  r[6] = (short)f2b(b.z); r[7] = (short)f2b(b.w);
  return r;
}
// async global->LDS, 16B per lane. Per-lane lds ptr must equal wave-uniform + lane*16.
static __device__ __forceinline__ void gload16(const u16* g, u16* l){
  __builtin_amdgcn_global_load_lds((const __attribute__((address_space(1))) void*)g,
                                   (__attribute__((address_space(3))) void*)l,
                                   16, 0, 0);
}

// ------------- fp32 -> bf16 bulk convert (8 elems/thread) ------------------
__global__ void convert_k(const float* __restrict__ in, u16* __restrict__ out,
                          int n8){
  const int i = blockIdx.x * blockDim.x + threadIdx.x;
  if (i < n8) ((s8b*)out)[i] = load8(in + (size_t)i * 8);
}

// ------------- transpose: in[K][N] fp32 -> out[N][K] bf16 ------------------
__global__ void transpose_k(const float* __restrict__ in, u16* __restrict__ out,
                            int K, int N){
  __shared__ u16 tile[32][33];
  const int n0 = blockIdx.x << 5, k0 = blockIdx.y << 5;
  const int tx = threadIdx.x, ty = threadIdx.y;   // block (32,8)
  #pragma unroll
  for (int i = ty; i < 32; i += 8)
    tile[i][tx] = f2b(in[(size_t)(k0 + i) * N + n0 + tx]);
  __syncthreads();
  #pragma unroll
  for (int i = ty; i < 32; i += 8)
    out[(size_t)(n0 + i) * K + k0 + tx] = tile[tx][i];
}

// ------------- fused Wq/Wk/Wv transpose into WT rows [0,2048|2048,2560|2560,3072)
__global__ void transpose3_k(const float* __restrict__ Wq,
                             const float* __restrict__ Wk,
                             const float* __restrict__ Wv,
                             u16* __restrict__ out){
  __shared__ u16 tile[32][33];
  int bx = blockIdx.x;
  const float* src; int N; int rowoff;
  if (bx < 64)      { src = Wq; N = 2048; rowoff = 0; }
  else if (bx < 80) { src = Wk; N = 512;  rowoff = 2048; bx -= 64; }
  else              { src = Wv; N = 512;  rowoff = 2560; bx -= 80; }
  const int n0 = bx << 5, k0 = blockIdx.y << 5;
  const int tx = threadIdx.x, ty = threadIdx.y;   // block (32,8)
  #pragma unroll
  for (int i = ty; i < 32; i += 8)
    tile[i][tx] = f2b(src[(size_t)(k0 + i) * N + n0 + tx]);
  __syncthreads();
  #pragma unroll
  for (int i = ty; i < 32; i += 8)
    out[(size_t)(rowoff + n0 + i) * 2048 + k0 + tx] = tile[tx][i];
}

// ------------- 8-wave MFMA GEMM, 128x128 tile, BK=32, 2-phase dbuf ---------
// A bf16 [M][K], Bt bf16 [Ntot][K]. 512 threads = 8 waves (2 m-rows x 4 n-cols),
// wave tile 64x32 (acc[4][2]). Double-buffered global_load_lds staging with
// counted vmcnt(2) + raw barriers: stage t+1 flies under ds_read+MFMA of t.
// MODE 0: fused QKV epilogue; MODE 1: fp32 row-major N=2048.
template <int MODE>
__global__ __launch_bounds__(512) void gemm8(const u16* __restrict__ A,
                                             const u16* __restrict__ Bt,
                                             u16* __restrict__ Cq,
                                             u16* __restrict__ Ck,
                                             u16* __restrict__ Cv,
                                             float* __restrict__ Cf,
                                             int M, int K){
  __shared__ __align__(16) u16 As[2][128 * 32];
  __shared__ __align__(16) u16 Bs[2][128 * 32];
  const int n0 = blockIdx.x << 7;
  const int m0 = blockIdx.y << 7;
  const int tid = threadIdx.x;
  const int wave = tid >> 6, lane = tid & 63;
  const int quad = lane >> 4, ln = lane & 15;
  const int wr = (wave >> 2) << 6;     // 0 / 64
  const int wc = (wave & 3) << 5;      // 0 / 32 / 64 / 96
  const int lr = tid >> 2, lc = (tid & 3) << 3;   // 128 rows x 32 cols staging

  f4 acc[4][2];
  #pragma unroll
  for (int i = 0; i < 4; ++i)
    #pragma unroll
    for (int j = 0; j < 2; ++j){ f4 z = {0.f,0.f,0.f,0.f}; acc[i][j] = z; }

  const u16* ag = A  + (size_t)(m0 + lr) * K + lc;
  const u16* bg = Bt + (size_t)(n0 + lr) * K + lc;
  const int NT = K >> 5;

  // prologue: stage tile 0 into buffer 0
  gload16(ag, As[0] + tid * 8);
  gload16(bg, Bs[0] + tid * 8);

  for (int t = 0; t < NT; ++t){
    const int cur = t & 1;
    // issue next stage (clamped on last iter; harmless re-load)
    const int kn = ((t + 1) < NT ? (t + 1) : t) << 5;
    gload16(ag + kn, As[cur ^ 1] + tid * 8);
    gload16(bg + kn, Bs[cur ^ 1] + tid * 8);
    // wait for PREVIOUS stage (2 newest loads stay in flight), then sync
    asm volatile("s_waitcnt vmcnt(2)" ::: "memory");
    __builtin_amdgcn_s_barrier();
    s8b af[4], bf[2];
    #pragma unroll
    for (int i = 0; i < 4; ++i) af[i] = *(const s8b*)&As[cur][(wr + i*16 + ln)*32 + quad*8];
    #pragma unroll
    for (int j = 0; j < 2; ++j) bf[j] = *(const s8b*)&Bs[cur][(wc + j*16 + ln)*32 + quad*8];
    #pragma unroll
    for (int i = 0; i < 4; ++i)
      #pragma unroll
      for (int j = 0; j < 2; ++j)
        acc[i][j] = mfma16(af[i], bf[j], acc[i][j]);
    // all my LDS reads retired; then sync so next stage may overwrite buf[cur]
    asm volatile("s_waitcnt lgkmcnt(0)" ::: "memory");
    __builtin_amdgcn_s_barrier();
  }
  // C/D layout: col = ln, row = quad*4 + r (m89/m91-verified)
  #pragma unroll
  for (int i = 0; i < 4; ++i)
    #pragma unroll
    for (int j = 0; j < 2; ++j)
      #pragma unroll
      for (int r = 0; r < 4; ++r){
        const int row = m0 + wr + i*16 + quad*4 + r;
        const int col = n0 + wc + j*16 + ln;
        const float v = acc[i][j][r];
        if (MODE == 1){
          Cf[(size_t)row * 2048 + col] = v;
        } else {
          if (col < 2048)       Cq[(size_t)row * 2048 + col]          = f2b(v);
          else if (col < 2560)  Ck[(size_t)row * 512  + (col - 2048)] = f2b(v);
          else                  Cv[(size_t)(col - 2560) * 2048 + row] = f2b(v);
        }
      }
}

// ------------- fused RoPE in place on q (16 heads) and k (4 heads) ---------
__global__ void rope2_k(u16* __restrict__ q, u16* __restrict__ k){
  const int s = blockIdx.x;
  #pragma unroll
  for (int it = 0; it < 5; ++it){
    const int p = it * 256 + threadIdx.x;          // 1024 q pairs + 256 k pairs
    int hh, i; u16* base;
    if (p < 1024){
      hh = p >> 6; i = p & 63;
      base = q + (size_t)s * 2048 + hh * 128 + i;
    } else {
      const int pp = p - 1024;
      hh = pp >> 6; i = pp & 63;
      base = k + (size_t)s * 512 + hh * 128 + i;
    }
    const float inv = __expf(-(float)i * 0.14391157f);  // 10000^(-i/64)
    const float ang = (float)s * inv;
    float c, sn;
    sincosf(ang, &sn, &c);
    const float x1 = b2f(base[0]), x2 = b2f(base[64]);
    base[0]  = f2b(x1 * c - x2 * sn);
    base[64] = f2b(x2 * c + x1 * sn);
  }
}

// ------------- MFMA diff-attention, 4-way split, f16-E-in-regs -------------
// grid 2048 = 16 heads x 128 q-groups of 16 rows. Wave w owns window quarter
// w (<=5 k-tiles of 32 cols). BRANCH-FREE: all 5 tile slots execute with
// clamped tile indices; dead slots are masked to E=0 (K/V addresses stay on
// valid, finite data). E=(e1,e2) stored as packed f16 pairs, pre-scaled by
// 1/16 (cancels exactly through l and il; f16-safe for |s|<13.8).
// Unshifted softmax; single-stage combine (3 LDS slots, 1 barrier).
__global__ __launch_bounds__(256) void attn_k(const u16* __restrict__ q,
                                              const u16* __restrict__ kk,
                                              const u16* __restrict__ vt,
                                              const float* __restrict__ lam,
                                              u16* __restrict__ ctx){
  const int h  = blockIdx.x >> 7;
  const int qt = blockIdx.x & 127;
  const int qb = qt << 4;                 // 16 q rows per block
  const int tid = threadIdx.x;
  const int w = tid >> 6, lane = tid & 63;
  const int quad = lane >> 4, ln = lane & 15;
  const int kvh = h >> 2;
  const float lam_h = lam[h];
  const float scale = 0.125f;   // 1/sqrt(64)

  __shared__ __align__(16) u16 p_lds[4][2][16][40];   // [wave][tt&1][row][col]
  __shared__ float s_l1[4][16], s_l2[4][16], s_den[4][16];
  __shared__ float s_acc[3][16][132];                 // 3 combine slots

  s8b qf[4];   // A-layout: m = ln, k-slot (quad, s)
  {
    const u16* qrow = q + (size_t)(qb + ln) * 2048 + h * 128 + quad * 8;
    #pragma unroll
    for (int s = 0; s < 4; ++s) qf[s] = *(const s8b*)(qrow + s * 32);
  }

  // k-tiles covering [max(0,qb-511), qb+15], split 4 ways across waves
  const int tlo = (qb > 511) ? ((qb - 511) >> 5) : 0;
  const int thi = ((qb + 15) >> 5) + 1;
  const int nt  = thi - tlo;                  // <= 17
  const int base = nt >> 2, rem = nt & 3;
  const int t0 = tlo + w * base + (w < rem ? w : rem);
  const int t1 = t0 + base + (w < rem ? 1 : 0);   // t1 - t0 <= 5
  const int nlive = t1 - t0;                      // may be 0
  const int tmax = nlive > 0 ? nlive - 1 : 0;

  // ---- Pass A: K loads + QK^T + exp; E packed f16 in registers ----
  h8 eh[5];      // sub 0: (e1,e2) x 4 rows, packed f16
  h8 eh2[5];     // sub 1
  float l1[4] = {0.f,0.f,0.f,0.f}, l2[4] = {0.f,0.f,0.f,0.f};
  #pragma unroll
  for (int tt = 0; tt < 5; ++tt){
    const int tc0 = t0 + (tt <= tmax ? tt : tmax);
    const int tcc = tc0 < 63 ? tc0 : 63;
    const int kcol0 = tcc << 5;
    const bool live = tt < nlive;
    #pragma unroll
    for (int sub = 0; sub < 2; ++sub){
      const u16* krow = kk + (size_t)(kcol0 + sub*16 + ln) * 512 + kvh * 128 + quad * 8;
      s8b kf0 = *(const s8b*)(krow);
      s8b kf1 = *(const s8b*)(krow + 32);
      s8b kf2 = *(const s8b*)(krow + 64);
      s8b kf3 = *(const s8b*)(krow + 96);
      f4 z = {0.f,0.f,0.f,0.f};
      f4 s1 = mfma16(qf[1], kf1, mfma16(qf[0], kf0, z));
      f4 s2 = mfma16(qf[3], kf3, mfma16(qf[2], kf2, z));
      const int col = kcol0 + sub*16 + ln;
      h8 ev;
      #pragma unroll
      for (int r = 0; r < 4; ++r){
        const int row = qb + quad*4 + r;
        const bool ok = live && (col <= row) && (col > row - 512);
        const float a = ok ? __expf(s1[r] * scale) * 0.0625f : 0.f;
        const float b = ok ? __expf(s2[r] * scale) * 0.0625f : 0.f;
        l1[r] += a; l2[r] += b;
        ev[2*r]   = (_Float16)a;
        ev[2*r+1] = (_Float16)b;
      }
      if (sub == 0) eh[tt] = ev; else eh2[tt] = ev;
    }
  }
  #pragma unroll
  for (int r = 0; r < 4; ++r){
    #pragma unroll
    for (int off = 1; off < 16; off <<= 1){
      l1[r] += __shfl_xor(l1[r], off, 16);
      l2[r] += __shfl_xor(l2[r], off, 16);
    }
  }
  if (ln == 0){
    #pragma unroll
    for (int r = 0; r < 4; ++r){
      s_l1[w][quad*4 + r] = l1[r];
      s_l2[w][quad*4 + r] = l2[r];
    }
  }
  __syncthreads();
  float il1[4], il2[4];
  #pragma unroll
  for (int r = 0; r < 4; ++r){
    const int rr = quad*4 + r;
    il1[r] = 1.f / (s_l1[0][rr] + s_l1[1][rr] + s_l1[2][rr] + s_l1[3][rr]);
    il2[r] = 1.f / (s_l2[0][rr] + s_l2[1][rr] + s_l2[2][rr] + s_l2[3][rr]);
  }

  // ---- Pass B: pd from packed E; p_lds transpose; PV ----
  f4 acc[8];
  #pragma unroll
  for (int dt = 0; dt < 8; ++dt){ f4 z = {0.f,0.f,0.f,0.f}; acc[dt] = z; }
  float den[4] = {0.f,0.f,0.f,0.f};

  #pragma unroll
  for (int tt = 0; tt < 5; ++tt){
    const int tc0 = t0 + (tt <= tmax ? tt : tmax);
    const int tcc = tc0 < 63 ? tc0 : 63;
    const int kcol0 = tcc << 5;
    #pragma unroll
    for (int sub = 0; sub < 2; ++sub){
      const h8 ev = (sub == 0) ? eh[tt] : eh2[tt];
      #pragma unroll
      for (int r = 0; r < 4; ++r){
        const float a = (float)ev[2*r];
        const float b = (float)ev[2*r+1];
        const float pd = fmaxf(a * il1[r] - lam_h * (b * il2[r]), 0.f);
        den[r] += pd;
        p_lds[w][tt & 1][quad*4 + r][sub*16 + ln] = f2b(pd);
      }
    }
    // per-wave LDS slice: within-wave ordering handled by lgkmcnt.
    s8b pf = *(const s8b*)&p_lds[w][tt & 1][ln][quad * 8];
    const u16* vbase = vt + (size_t)(kvh*128 + ln) * 2048 + kcol0 + quad * 8;
    #pragma unroll
    for (int dt = 0; dt < 8; ++dt){
      s8b vf = *(const s8b*)(vbase + (size_t)dt * 16 * 2048);
      acc[dt] = mfma16(pf, vf, acc[dt]);
    }
  }

  #pragma unroll
  for (int r = 0; r < 4; ++r)
    #pragma unroll
    for (int off = 1; off < 16; off <<= 1)
      den[r] += __shfl_xor(den[r], off, 16);
  if (ln == 0){
    #pragma unroll
    for (int r = 0; r < 4; ++r) s_den[w][quad*4 + r] = den[r];
  }
  // single-stage combine: waves 1..3 -> slots, one barrier, wave 0 sums.
  if (w > 0){
    #pragma unroll
    for (int dt = 0; dt < 8; ++dt)
      #pragma unroll
      for (int r = 0; r < 4; ++r)
        s_acc[w - 1][quad*4 + r][dt*16 + ln] = acc[dt][r];
  }
  __syncthreads();
  if (w == 0){
    #pragma unroll
    for (int dt = 0; dt < 8; ++dt)
      #pragma unroll
      for (int r = 0; r < 4; ++r)
        acc[dt][r] += s_acc[0][quad*4 + r][dt*16 + ln]
                    + s_acc[1][quad*4 + r][dt*16 + ln]
                    + s_acc[2][quad*4 + r][dt*16 + ln];
    #pragma unroll
    for (int r = 0; r < 4; ++r){
      const int rr = quad*4 + r;
      const float dn = 1.f / (s_den[0][rr] + s_den[1][rr] + s_den[2][rr] + s_den[3][rr] + 1e-6f);
      const int row = qb + rr;
      u16* orow = ctx + (size_t)row * 2048 + h * 128 + ln;
      #pragma unroll
      for (int dt = 0; dt < 8; ++dt)
        orow[dt * 16] = f2b(acc[dt][r] * dn);
    }
  }
}

// ------------- launch ------------------------------------------------------
extern "C" void kernel_launch(void* const* d_in, const int* in_sizes, int n_in,
                              void* d_out, int out_size, void* d_ws, size_t ws_size,
                              hipStream_t stream){
  (void)in_sizes; (void)n_in; (void)out_size; (void)ws_size;
  const float* x   = (const float*)d_in[0];
  const float* Wq  = (const float*)d_in[1];
  const float* Wk  = (const float*)d_in[2];
  const float* Wv  = (const float*)d_in[3];
  const float* Wo  = (const float*)d_in[4];
  const float* lam = (const float*)d_in[5];
  char* ws = (char*)d_ws;
  // ws (<=17.1 MB of the 20 MB budget):
  //   WT  [0, 12.6)  fused [WqT;WkT;WvT] = 3072x2048 bf16
  //   kb  [13, 15)   roped k
  //   vtb [15, 17)   v^T
  //   ctx [0, 8)     reuse of WT after fused gemm
  //   WoT [8, 16)    reuse after attn (kb/vtb dead)
  u16* WT  = (u16*)(ws);
  u16* kb  = (u16*)(ws + (size_t)(13u << 20));
  u16* vtb = (u16*)(ws + (size_t)(15u << 20));
  u16* ctx = WT;
  u16* WoT = (u16*)(ws + (size_t)( 8u << 20));
  // d_out (16 MB fp32): xb [0,8), qb [8,16). Both dead before the final gemm,
  // which reads only ctx/WoT (ws) and overwrites all of d_out.
  u16* xb  = (u16*)d_out;
  u16* qb  = (u16*)((char*)d_out + (size_t)(8u << 20));
  float* out = (float*)d_out;

  const dim3 tb(32, 8);
  convert_k<<<2048, 256, 0, stream>>>(x, xb, 2048 * 2048 / 8);
  // fused weight transpose: WT rows [0,2048)=WqT, [2048,2560)=WkT, [2560,3072)=WvT
  transpose3_k<<<dim3(96, 64), tb, 0, stream>>>(Wq, Wk, Wv, WT);
  // fused QKV projection: [q | k | v^T]
  gemm8<0><<<dim3(24, 16), 512, 0, stream>>>(xb, WT, qb, kb, vtb, nullptr, 2048, 2048);
  // fused RoPE (q and k)
  rope2_k<<<2048, 256, 0, stream>>>(qb, kb);
  // diff-attention -> ctx
  attn_k<<<2048, 256, 0, stream>>>(qb, kb, vtb, lam, ctx);
  // out = ctx @ Wo
  transpose_k<<<dim3(64, 64), tb, 0, stream>>>(Wo, WoT, 2048, 2048);
  gemm8<1><<<dim3(16, 16), 512, 0, stream>>>(ctx, WoT, nullptr, nullptr, nullptr, out, 2048, 2048);
}

// Round 6
// 258.225 us; speedup vs baseline: 1.1566x; 1.1566x over previous
//
#include <hip/hip_runtime.h>

typedef unsigned short u16;
typedef __attribute__((ext_vector_type(8))) short s8b;       // 8 x bf16 bits
typedef __attribute__((ext_vector_type(4))) float f4;

static __device__ __forceinline__ float b2f(u16 u){
  return __uint_as_float(((unsigned int)u) << 16);
}
static __device__ __forceinline__ u16 f2b(float f){
  unsigned int u = __float_as_uint(f);
  u = (u + 0x7FFFu + ((u >> 16) & 1u)) >> 16;   // RNE
  return (u16)u;
}
static __device__ __forceinline__ f4 mfma16(s8b a, s8b b, f4 c){
  return __builtin_amdgcn_mfma_f32_16x16x32_bf16(a, b, c, 0, 0, 0);
}
static __device__ __forceinline__ s8b load8(const float* p){
  float4 a = ((const float4*)p)[0];
  float4 b = ((const float4*)p)[1];
  s8b r;
  r[0] = (short)f2b(a.x); r[1] = (short)f2b(a.y);
  r[2] = (short)f2b(a.z); r[3] = (short)f2b(a.w);
  r[4] = (short)f2b(b.x); r[5] = (short)f2b(b.y);
  r[6] = (short)f2b(b.z); r[7] = (short)f2b(b.w);
  return r;
}
// async global->LDS, 16B per lane. Per-lane lds ptr must equal wave-uniform + lane*16.
static __device__ __forceinline__ void gload16(const u16* g, u16* l){
  __builtin_amdgcn_global_load_lds((const __attribute__((address_space(1))) void*)g,
                                   (__attribute__((address_space(3))) void*)l,
                                   16, 0, 0);
}

// ------------- fp32 -> bf16 bulk convert (8 elems/thread) ------------------
__global__ void convert_k(const float* __restrict__ in, u16* __restrict__ out,
                          int n8){
  const int i = blockIdx.x * blockDim.x + threadIdx.x;
  if (i < n8) ((s8b*)out)[i] = load8(in + (size_t)i * 8);
}

// ------------- transpose: in[K][N] fp32 -> out[N][K] bf16 ------------------
__global__ void transpose_k(const float* __restrict__ in, u16* __restrict__ out,
                            int K, int N){
  __shared__ u16 tile[32][33];
  const int n0 = blockIdx.x << 5, k0 = blockIdx.y << 5;
  const int tx = threadIdx.x, ty = threadIdx.y;   // block (32,8)
  #pragma unroll
  for (int i = ty; i < 32; i += 8)
    tile[i][tx] = f2b(in[(size_t)(k0 + i) * N + n0 + tx]);
  __syncthreads();
  #pragma unroll
  for (int i = ty; i < 32; i += 8)
    out[(size_t)(n0 + i) * K + k0 + tx] = tile[tx][i];
}

// ------------- fused Wq/Wk/Wv transpose into WT rows [0,2048|2048,2560|2560,3072)
__global__ void transpose3_k(const float* __restrict__ Wq,
                             const float* __restrict__ Wk,
                             const float* __restrict__ Wv,
                             u16* __restrict__ out){
  __shared__ u16 tile[32][33];
  int bx = blockIdx.x;
  const float* src; int N; int rowoff;
  if (bx < 64)      { src = Wq; N = 2048; rowoff = 0; }
  else if (bx < 80) { src = Wk; N = 512;  rowoff = 2048; bx -= 64; }
  else              { src = Wv; N = 512;  rowoff = 2560; bx -= 80; }
  const int n0 = bx << 5, k0 = blockIdx.y << 5;
  const int tx = threadIdx.x, ty = threadIdx.y;   // block (32,8)
  #pragma unroll
  for (int i = ty; i < 32; i += 8)
    tile[i][tx] = f2b(src[(size_t)(k0 + i) * N + n0 + tx]);
  __syncthreads();
  #pragma unroll
  for (int i = ty; i < 32; i += 8)
    out[(size_t)(rowoff + n0 + i) * 2048 + k0 + tx] = tile[tx][i];
}

// ------------- 8-wave MFMA GEMM, 128x128 tile, BK=32, 2-phase dbuf ---------
// (unchanged from R5 — ran clean, +~6us vs single-buffer)
template <int MODE>
__global__ __launch_bounds__(512) void gemm8(const u16* __restrict__ A,
                                             const u16* __restrict__ Bt,
                                             u16* __restrict__ Cq,
                                             u16* __restrict__ Ck,
                                             u16* __restrict__ Cv,
                                             float* __restrict__ Cf,
                                             int M, int K){
  __shared__ __align__(16) u16 As[2][128 * 32];
  __shared__ __align__(16) u16 Bs[2][128 * 32];
  const int n0 = blockIdx.x << 7;
  const int m0 = blockIdx.y << 7;
  const int tid = threadIdx.x;
  const int wave = tid >> 6, lane = tid & 63;
  const int quad = lane >> 4, ln = lane & 15;
  const int wr = (wave >> 2) << 6;     // 0 / 64
  const int wc = (wave & 3) << 5;      // 0 / 32 / 64 / 96
  const int lr = tid >> 2, lc = (tid & 3) << 3;   // 128 rows x 32 cols staging

  f4 acc[4][2];
  #pragma unroll
  for (int i = 0; i < 4; ++i)
    #pragma unroll
    for (int j = 0; j < 2; ++j){ f4 z = {0.f,0.f,0.f,0.f}; acc[i][j] = z; }

  const u16* ag = A  + (size_t)(m0 + lr) * K + lc;
  const u16* bg = Bt + (size_t)(n0 + lr) * K + lc;
  const int NT = K >> 5;

  gload16(ag, As[0] + tid * 8);
  gload16(bg, Bs[0] + tid * 8);

  for (int t = 0; t < NT; ++t){
    const int cur = t & 1;
    const int kn = ((t + 1) < NT ? (t + 1) : t) << 5;
    gload16(ag + kn, As[cur ^ 1] + tid * 8);
    gload16(bg + kn, Bs[cur ^ 1] + tid * 8);
    asm volatile("s_waitcnt vmcnt(2)" ::: "memory");
    __builtin_amdgcn_s_barrier();
    s8b af[4], bf[2];
    #pragma unroll
    for (int i = 0; i < 4; ++i) af[i] = *(const s8b*)&As[cur][(wr + i*16 + ln)*32 + quad*8];
    #pragma unroll
    for (int j = 0; j < 2; ++j) bf[j] = *(const s8b*)&Bs[cur][(wc + j*16 + ln)*32 + quad*8];
    #pragma unroll
    for (int i = 0; i < 4; ++i)
      #pragma unroll
      for (int j = 0; j < 2; ++j)
        acc[i][j] = mfma16(af[i], bf[j], acc[i][j]);
    asm volatile("s_waitcnt lgkmcnt(0)" ::: "memory");
    __builtin_amdgcn_s_barrier();
  }
  #pragma unroll
  for (int i = 0; i < 4; ++i)
    #pragma unroll
    for (int j = 0; j < 2; ++j)
      #pragma unroll
      for (int r = 0; r < 4; ++r){
        const int row = m0 + wr + i*16 + quad*4 + r;
        const int col = n0 + wc + j*16 + ln;
        const float v = acc[i][j][r];
        if (MODE == 1){
          Cf[(size_t)row * 2048 + col] = v;
        } else {
          if (col < 2048)       Cq[(size_t)row * 2048 + col]          = f2b(v);
          else if (col < 2560)  Ck[(size_t)row * 512  + (col - 2048)] = f2b(v);
          else                  Cv[(size_t)(col - 2560) * 2048 + row] = f2b(v);
        }
      }
}

// ------------- fused RoPE in place on q (16 heads) and k (4 heads) ---------
__global__ void rope2_k(u16* __restrict__ q, u16* __restrict__ k){
  const int s = blockIdx.x;
  #pragma unroll
  for (int it = 0; it < 5; ++it){
    const int p = it * 256 + threadIdx.x;          // 1024 q pairs + 256 k pairs
    int hh, i; u16* base;
    if (p < 1024){
      hh = p >> 6; i = p & 63;
      base = q + (size_t)s * 2048 + hh * 128 + i;
    } else {
      const int pp = p - 1024;
      hh = pp >> 6; i = pp & 63;
      base = k + (size_t)s * 512 + hh * 128 + i;
    }
    const float inv = __expf(-(float)i * 0.14391157f);  // 10000^(-i/64)
    const float ang = (float)s * inv;
    float c, sn;
    sincosf(ang, &sn, &c);
    const float x1 = b2f(base[0]), x2 = b2f(base[64]);
    base[0]  = f2b(x1 * c - x2 * sn);
    base[64] = f2b(x2 * c + x1 * sn);
  }
}

// ------------- MFMA diff-attention v6: LDS-staged K/V, counted-vmcnt -------
// grid 512 = 16 heads x 32 q-tiles of 64 rows; 4 waves, wave w owns rows
// [qt0+16w, +16) entirely (no cross-wave combine). All waves iterate the
// block-union window tiles [tlo, thi). K-tile [32][128] and V-tile [128][32]
// staged via global_load_lds with PRE-SWIZZLED global source (T21): LDS dest
// stays linear; reads XOR the 16B-slot index (K: ^row&7, V: ^row&3) to kill
// the row-major bank conflict. 2-phase dbuf, vmcnt(2)/(4) counted waits,
// exact gemm8 barrier discipline. Pass A: l1/l2 sums. Pass B: recompute
// QK^T from LDS (E doesn't fit regs at 18 tiles), P, PV. Unshifted softmax.
__global__ __launch_bounds__(256) void attn_k(const u16* __restrict__ q,
                                              const u16* __restrict__ kk,
                                              const u16* __restrict__ vt,
                                              const float* __restrict__ lam,
                                              u16* __restrict__ ctx){
  const int h   = blockIdx.x >> 5;
  const int qt  = blockIdx.x & 31;
  const int qt0 = qt << 6;
  const int tid = threadIdx.x;
  const int w = tid >> 6, lane = tid & 63;
  const int quad = lane >> 4, ln = lane & 15;
  const int kvh = h >> 2;
  const float lam_h = lam[h];
  const float scale = 0.125f;   // 1/sqrt(64)
  const int qbw = qt0 + (w << 4);           // this wave's 16 q rows

  __shared__ __align__(16) u16 Ks[2][32 * 128];   // 16 KB
  __shared__ __align__(16) u16 Vs[2][128 * 32];   // 16 KB
  __shared__ __align__(16) u16 p_lds[4][2][16][40];

  s8b qf[4];   // A-layout: m = ln, k-slot (quad, s)
  {
    const u16* qrow = q + (size_t)(qbw + ln) * 2048 + h * 128 + quad * 8;
    #pragma unroll
    for (int s = 0; s < 4; ++s) qf[s] = *(const s8b*)(qrow + s * 32);
  }

  const int tlo = (qt0 > 511) ? ((qt0 - 511) >> 5) : 0;
  const int thi = ((qt0 + 63) >> 5) + 1;    // <= 64; nt <= 18

  // ---- staging (block-cooperative, 512 x 16B slots each) ----
  // K linear slot (row, c16): row = slot>>4, c16 = slot&15; source col16 = c16 ^ (row&7)
#define STAGE_K(buf, t) {                                                         \
    const int kc = (t) << 5;                                                      \
    _Pragma("unroll")                                                             \
    for (int i_ = 0; i_ < 2; ++i_){                                               \
      const int slot = tid + i_ * 256;                                            \
      const int row_ = slot >> 4, c16_ = slot & 15;                               \
      const u16* src_ = kk + (size_t)(kc + row_) * 512 + kvh * 128                \
                        + ((c16_ ^ (row_ & 7)) << 3);                             \
      gload16(src_, &Ks[buf][slot * 8]);                                          \
    } }
  // V linear slot (row, c16): row = slot>>2, c16 = slot&3; source col16 = c16 ^ (row&3)
#define STAGE_V(buf, t) {                                                         \
    const int kc = (t) << 5;                                                      \
    _Pragma("unroll")                                                             \
    for (int i_ = 0; i_ < 2; ++i_){                                               \
      const int slot = tid + i_ * 256;                                            \
      const int row_ = slot >> 2, c16_ = slot & 3;                                \
      const u16* src_ = vt + (size_t)(kvh * 128 + row_) * 2048 + kc               \
                        + ((c16_ ^ (row_ & 3)) << 3);                             \
      gload16(src_, &Vs[buf][slot * 8]);                                          \
    } }

  // ---- Pass A: denominators (unshifted) ----
  float l1[4] = {0.f,0.f,0.f,0.f}, l2[4] = {0.f,0.f,0.f,0.f};
  STAGE_K(0, tlo);
  asm volatile("s_waitcnt vmcnt(0)" ::: "memory");
  __builtin_amdgcn_s_barrier();
  for (int t = tlo; t < thi; ++t){
    const int cur = (t - tlo) & 1;
    if (t + 1 < thi){
      STAGE_K(cur ^ 1, t + 1);
      asm volatile("s_waitcnt vmcnt(2)" ::: "memory");
    } else {
      asm volatile("s_waitcnt vmcnt(0)" ::: "memory");
    }
    __builtin_amdgcn_s_barrier();
    const int kcol0 = t << 5;
    if (kcol0 <= qbw + 15 && kcol0 + 31 >= qbw - 511){
      #pragma unroll
      for (int sub = 0; sub < 2; ++sub){
        const int krow = (sub*16 + ln) * 128;
        s8b kf0 = *(const s8b*)&Ks[cur][krow + (((quad +  0) ^ (ln & 7)) << 3)];
        s8b kf1 = *(const s8b*)&Ks[cur][krow + (((quad +  4) ^ (ln & 7)) << 3)];
        s8b kf2 = *(const s8b*)&Ks[cur][krow + (((quad +  8) ^ (ln & 7)) << 3)];
        s8b kf3 = *(const s8b*)&Ks[cur][krow + (((quad + 12) ^ (ln & 7)) << 3)];
        f4 z = {0.f,0.f,0.f,0.f};
        f4 s1 = mfma16(qf[1], kf1, mfma16(qf[0], kf0, z));
        f4 s2 = mfma16(qf[3], kf3, mfma16(qf[2], kf2, z));
        const int col = kcol0 + sub*16 + ln;
        #pragma unroll
        for (int r = 0; r < 4; ++r){
          const int row = qbw + quad*4 + r;
          if (col <= row && col > row - 512){
            l1[r] += __expf(s1[r] * scale);
            l2[r] += __expf(s2[r] * scale);
          }
        }
      }
    }
    asm volatile("s_waitcnt lgkmcnt(0)" ::: "memory");
    __builtin_amdgcn_s_barrier();
  }
  #pragma unroll
  for (int r = 0; r < 4; ++r){
    #pragma unroll
    for (int off = 1; off < 16; off <<= 1){
      l1[r] += __shfl_xor(l1[r], off, 16);
      l2[r] += __shfl_xor(l2[r], off, 16);
    }
  }
  float il1[4], il2[4];
  #pragma unroll
  for (int r = 0; r < 4; ++r){ il1[r] = 1.f / l1[r]; il2[r] = 1.f / l2[r]; }

  // ---- Pass B: recompute QK^T, P = relu(p1 - lam*p2), PV, row sums ----
  f4 acc[8];
  #pragma unroll
  for (int dt = 0; dt < 8; ++dt){ f4 z = {0.f,0.f,0.f,0.f}; acc[dt] = z; }
  float den[4] = {0.f,0.f,0.f,0.f};

  STAGE_K(0, tlo);
  STAGE_V(0, tlo);
  asm volatile("s_waitcnt vmcnt(0)" ::: "memory");
  __builtin_amdgcn_s_barrier();
  for (int t = tlo; t < thi; ++t){
    const int cur = (t - tlo) & 1;
    if (t + 1 < thi){
      STAGE_K(cur ^ 1, t + 1);
      STAGE_V(cur ^ 1, t + 1);
      asm volatile("s_waitcnt vmcnt(4)" ::: "memory");
    } else {
      asm volatile("s_waitcnt vmcnt(0)" ::: "memory");
    }
    __builtin_amdgcn_s_barrier();
    const int kcol0 = t << 5;
    if (kcol0 <= qbw + 15 && kcol0 + 31 >= qbw - 511){
      #pragma unroll
      for (int sub = 0; sub < 2; ++sub){
        const int krow = (sub*16 + ln) * 128;
        s8b kf0 = *(const s8b*)&Ks[cur][krow + (((quad +  0) ^ (ln & 7)) << 3)];
        s8b kf1 = *(const s8b*)&Ks[cur][krow + (((quad +  4) ^ (ln & 7)) << 3)];
        s8b kf2 = *(const s8b*)&Ks[cur][krow + (((quad +  8) ^ (ln & 7)) << 3)];
        s8b kf3 = *(const s8b*)&Ks[cur][krow + (((quad + 12) ^ (ln & 7)) << 3)];
        f4 z = {0.f,0.f,0.f,0.f};
        f4 s1 = mfma16(qf[1], kf1, mfma16(qf[0], kf0, z));
        f4 s2 = mfma16(qf[3], kf3, mfma16(qf[2], kf2, z));
        const int col = kcol0 + sub*16 + ln;
        #pragma unroll
        for (int r = 0; r < 4; ++r){
          const int row = qbw + quad*4 + r;
          float pd = 0.f;
          if (col <= row && col > row - 512){
            const float p1 = __expf(s1[r] * scale) * il1[r];
            const float p2 = __expf(s2[r] * scale) * il2[r];
            pd = fmaxf(p1 - lam_h * p2, 0.f);
          }
          den[r] += pd;
          p_lds[w][(t - tlo) & 1][quad*4 + r][sub*16 + ln] = f2b(pd);
        }
      }
      // per-wave LDS slice: within-wave ordering handled by lgkmcnt.
      s8b pf = *(const s8b*)&p_lds[w][(t - tlo) & 1][ln][quad * 8];
      #pragma unroll
      for (int dt = 0; dt < 8; ++dt){
        s8b vf = *(const s8b*)&Vs[cur][(dt*16 + ln)*32 + ((quad ^ (ln & 3)) << 3)];
        acc[dt] = mfma16(pf, vf, acc[dt]);
      }
    }
    asm volatile("s_waitcnt lgkmcnt(0)" ::: "memory");
    __builtin_amdgcn_s_barrier();
  }

  #pragma unroll
  for (int r = 0; r < 4; ++r)
    #pragma unroll
    for (int off = 1; off < 16; off <<= 1)
      den[r] += __shfl_xor(den[r], off, 16);
  #pragma unroll
  for (int r = 0; r < 4; ++r){
    const float dn = 1.f / (den[r] + 1e-6f);
    const int row = qbw + quad*4 + r;
    u16* orow = ctx + (size_t)row * 2048 + h * 128 + ln;
    #pragma unroll
    for (int dt = 0; dt < 8; ++dt)
      orow[dt * 16] = f2b(acc[dt][r] * dn);
  }
#undef STAGE_K
#undef STAGE_V
}

// ------------- launch ------------------------------------------------------
extern "C" void kernel_launch(void* const* d_in, const int* in_sizes, int n_in,
                              void* d_out, int out_size, void* d_ws, size_t ws_size,
                              hipStream_t stream){
  (void)in_sizes; (void)n_in; (void)out_size; (void)ws_size;
  const float* x   = (const float*)d_in[0];
  const float* Wq  = (const float*)d_in[1];
  const float* Wk  = (const float*)d_in[2];
  const float* Wv  = (const float*)d_in[3];
  const float* Wo  = (const float*)d_in[4];
  const float* lam = (const float*)d_in[5];
  char* ws = (char*)d_ws;
  // ws (<=17.1 MB of the 20 MB budget):
  //   WT  [0, 12.6)  fused [WqT;WkT;WvT] = 3072x2048 bf16
  //   kb  [13, 15)   roped k
  //   vtb [15, 17)   v^T
  //   ctx [0, 8)     reuse of WT after fused gemm
  //   WoT [8, 16)    reuse after attn (kb/vtb dead)
  u16* WT  = (u16*)(ws);
  u16* kb  = (u16*)(ws + (size_t)(13u << 20));
  u16* vtb = (u16*)(ws + (size_t)(15u << 20));
  u16* ctx = WT;
  u16* WoT = (u16*)(ws + (size_t)( 8u << 20));
  // d_out (16 MB fp32): xb [0,8), qb [8,16). Both dead before the final gemm,
  // which reads only ctx/WoT (ws) and overwrites all of d_out.
  u16* xb  = (u16*)d_out;
  u16* qb  = (u16*)((char*)d_out + (size_t)(8u << 20));
  float* out = (float*)d_out;

  const dim3 tb(32, 8);
  convert_k<<<2048, 256, 0, stream>>>(x, xb, 2048 * 2048 / 8);
  // fused weight transpose: WT rows [0,2048)=WqT, [2048,2560)=WkT, [2560,3072)=WvT
  transpose3_k<<<dim3(96, 64), tb, 0, stream>>>(Wq, Wk, Wv, WT);
  // fused QKV projection: [q | k | v^T]
  gemm8<0><<<dim3(24, 16), 512, 0, stream>>>(xb, WT, qb, kb, vtb, nullptr, 2048, 2048);
  // fused RoPE (q and k)
  rope2_k<<<2048, 256, 0, stream>>>(qb, kb);
  // diff-attention -> ctx (64 q-rows/block, LDS-staged K/V pipeline)
  attn_k<<<512, 256, 0, stream>>>(qb, kb, vtb, lam, ctx);
  // out = ctx @ Wo
  transpose_k<<<dim3(64, 64), tb, 0, stream>>>(Wo, WoT, 2048, 2048);
  gemm8<1><<<dim3(16, 16), 512, 0, stream>>>(ctx, WoT, nullptr, nullptr, nullptr, out, 2048, 2048);
}

// Round 8
// 242.724 us; speedup vs baseline: 1.2305x; 1.0639x over previous
//
#include <hip/hip_runtime.h>

typedef unsigned short u16;
typedef __attribute__((ext_vector_type(8))) short s8b;       // 8 x bf16 bits
typedef __attribute__((ext_vector_type(4))) float f4;
typedef __attribute__((ext_vector_type(8))) _Float16 h8;     // 8 x f16

static __device__ __forceinline__ float b2f(u16 u){
  return __uint_as_float(((unsigned int)u) << 16);
}
static __device__ __forceinline__ u16 f2b(float f){
  unsigned int u = __float_as_uint(f);
  u = (u + 0x7FFFu + ((u >> 16) & 1u)) >> 16;   // RNE
  return (u16)u;
}
static __device__ __forceinline__ f4 mfma16(s8b a, s8b b, f4 c){
  return __builtin_amdgcn_mfma_f32_16x16x32_bf16(a, b, c, 0, 0, 0);
}
static __device__ __forceinline__ s8b load8(const float* p){
  float4 a = ((const float4*)p)[0];
  float4 b = ((const float4*)p)[1];
  s8b r;
  r[0] = (short)f2b(a.x); r[1] = (short)f2b(a.y);
  r[2] = (short)f2b(a.z); r[3] = (short)f2b(a.w);
  r[4] = (short)f2b(b.x); r[5] = (short)f2b(b.y);
  r[6] = (short)f2b(b.z); r[7] = (short)f2b(b.w);
  return r;
}
// async global->LDS, 16B per lane. Per-lane lds ptr must equal wave-uniform + lane*16.
static __device__ __forceinline__ void gload16(const u16* g, u16* l){
  __builtin_amdgcn_global_load_lds((const __attribute__((address_space(1))) void*)g,
                                   (__attribute__((address_space(3))) void*)l,
                                   16, 0, 0);
}

// ------------- fp32 -> bf16 bulk convert (8 elems/thread) ------------------
__global__ void convert_k(const float* __restrict__ in, u16* __restrict__ out,
                          int n8){
  const int i = blockIdx.x * blockDim.x + threadIdx.x;
  if (i < n8) ((s8b*)out)[i] = load8(in + (size_t)i * 8);
}

// ------------- transpose: in[K][N] fp32 -> out[N][K] bf16 ------------------
__global__ void transpose_k(const float* __restrict__ in, u16* __restrict__ out,
                            int K, int N){
  __shared__ u16 tile[32][33];
  const int n0 = blockIdx.x << 5, k0 = blockIdx.y << 5;
  const int tx = threadIdx.x, ty = threadIdx.y;   // block (32,8)
  #pragma unroll
  for (int i = ty; i < 32; i += 8)
    tile[i][tx] = f2b(in[(size_t)(k0 + i) * N + n0 + tx]);
  __syncthreads();
  #pragma unroll
  for (int i = ty; i < 32; i += 8)
    out[(size_t)(n0 + i) * K + k0 + tx] = tile[tx][i];
}

// ------------- fused Wq/Wk/Wv transpose into WT rows [0,2048|2048,2560|2560,3072)
__global__ void transpose3_k(const float* __restrict__ Wq,
                             const float* __restrict__ Wk,
                             const float* __restrict__ Wv,
                             u16* __restrict__ out){
  __shared__ u16 tile[32][33];
  int bx = blockIdx.x;
  const float* src; int N; int rowoff;
  if (bx < 64)      { src = Wq; N = 2048; rowoff = 0; }
  else if (bx < 80) { src = Wk; N = 512;  rowoff = 2048; bx -= 64; }
  else              { src = Wv; N = 512;  rowoff = 2560; bx -= 80; }
  const int n0 = bx << 5, k0 = blockIdx.y << 5;
  const int tx = threadIdx.x, ty = threadIdx.y;   // block (32,8)
  #pragma unroll
  for (int i = ty; i < 32; i += 8)
    tile[i][tx] = f2b(src[(size_t)(k0 + i) * N + n0 + tx]);
  __syncthreads();
  #pragma unroll
  for (int i = ty; i < 32; i += 8)
    out[(size_t)(rowoff + n0 + i) * 2048 + k0 + tx] = tile[tx][i];
}

// ------------- 8-wave MFMA GEMM, 128x128 tile, BK=32, 2-phase dbuf ---------
// R7: LDS XOR-swizzle (T2/T21 both-sides). Stored granule s of row r holds
// source granule s ^ ((r>>1)&3); LDS dest linear (gload_lds requirement),
// swizzle applied on the GLOBAL source (same 64B line -> coalescing intact)
// and on the ds_read granule index. Quarter-wave bank spread 2-of-8 -> 8-of-8.
template <int MODE>
__global__ __launch_bounds__(512) void gemm8(const u16* __restrict__ A,
                                             const u16* __restrict__ Bt,
                                             u16* __restrict__ Cq,
                                             u16* __restrict__ Ck,
                                             u16* __restrict__ Cv,
                                             float* __restrict__ Cf,
                                             int M, int K){
  __shared__ __align__(16) u16 As[2][128 * 32];
  __shared__ __align__(16) u16 Bs[2][128 * 32];
  const int n0 = blockIdx.x << 7;
  const int m0 = blockIdx.y << 7;
  const int tid = threadIdx.x;
  const int wave = tid >> 6, lane = tid & 63;
  const int quad = lane >> 4, ln = lane & 15;
  const int wr = (wave >> 2) << 6;     // 0 / 64
  const int wc = (wave & 3) << 5;      // 0 / 32 / 64 / 96
  const int lr = tid >> 2;                        // staged row
  const int lc = (((tid & 3) ^ ((tid >> 3) & 3)) << 3);  // pre-swizzled src granule

  f4 acc[4][2];
  #pragma unroll
  for (int i = 0; i < 4; ++i)
    #pragma unroll
    for (int j = 0; j < 2; ++j){ f4 z = {0.f,0.f,0.f,0.f}; acc[i][j] = z; }

  const u16* ag = A  + (size_t)(m0 + lr) * K + lc;
  const u16* bg = Bt + (size_t)(n0 + lr) * K + lc;
  const int NT = K >> 5;
  const int rsw = ((ln >> 1) & 3) << 3;           // read-side XOR partner

  gload16(ag, As[0] + tid * 8);
  gload16(bg, Bs[0] + tid * 8);

  for (int t = 0; t < NT; ++t){
    const int cur = t & 1;
    const int kn = ((t + 1) < NT ? (t + 1) : t) << 5;
    gload16(ag + kn, As[cur ^ 1] + tid * 8);
    gload16(bg + kn, Bs[cur ^ 1] + tid * 8);
    asm volatile("s_waitcnt vmcnt(2)" ::: "memory");
    __builtin_amdgcn_s_barrier();
    s8b af[4], bf[2];
    #pragma unroll
    for (int i = 0; i < 4; ++i)
      af[i] = *(const s8b*)&As[cur][(wr + i*16 + ln)*32 + ((quad*8) ^ rsw)];
    #pragma unroll
    for (int j = 0; j < 2; ++j)
      bf[j] = *(const s8b*)&Bs[cur][(wc + j*16 + ln)*32 + ((quad*8) ^ rsw)];
    #pragma unroll
    for (int i = 0; i < 4; ++i)
      #pragma unroll
      for (int j = 0; j < 2; ++j)
        acc[i][j] = mfma16(af[i], bf[j], acc[i][j]);
    asm volatile("s_waitcnt lgkmcnt(0)" ::: "memory");
    __builtin_amdgcn_s_barrier();
  }
  #pragma unroll
  for (int i = 0; i < 4; ++i)
    #pragma unroll
    for (int j = 0; j < 2; ++j)
      #pragma unroll
      for (int r = 0; r < 4; ++r){
        const int row = m0 + wr + i*16 + quad*4 + r;
        const int col = n0 + wc + j*16 + ln;
        const float v = acc[i][j][r];
        if (MODE == 1){
          Cf[(size_t)row * 2048 + col] = v;
        } else {
          if (col < 2048)       Cq[(size_t)row * 2048 + col]          = f2b(v);
          else if (col < 2560)  Ck[(size_t)row * 512  + (col - 2048)] = f2b(v);
          else                  Cv[(size_t)(col - 2560) * 2048 + row] = f2b(v);
        }
      }
}

// ------------- fused RoPE in place on q (16 heads) and k (4 heads) ---------
__global__ void rope2_k(u16* __restrict__ q, u16* __restrict__ k){
  const int s = blockIdx.x;
  #pragma unroll
  for (int it = 0; it < 5; ++it){
    const int p = it * 256 + threadIdx.x;          // 1024 q pairs + 256 k pairs
    int hh, i; u16* base;
    if (p < 1024){
      hh = p >> 6; i = p & 63;
      base = q + (size_t)s * 2048 + hh * 128 + i;
    } else {
      const int pp = p - 1024;
      hh = pp >> 6; i = pp & 63;
      base = k + (size_t)s * 512 + hh * 128 + i;
    }
    const float inv = __expf(-(float)i * 0.14391157f);  // 10000^(-i/64)
    const float ang = (float)s * inv;
    float c, sn;
    sincosf(ang, &sn, &c);
    const float x1 = b2f(base[0]), x2 = b2f(base[64]);
    base[0]  = f2b(x1 * c - x2 * sn);
    base[64] = f2b(x2 * c + x1 * sn);
  }
}

// ------------- MFMA diff-attention v7: single-QK, f16 E-in-regs ------------
// grid 512 = 16 heads x 32 q-tiles of 64 rows; 4 waves, wave w owns rows
// [qt0+16w,+16). Pass A: K staged (dbuf, vmcnt(2)); QK^T + exp once; E=(e1,e2)
// packed f16 x (1/16 prescale, cancels via l/il) in 18 static reg slots
// (<=17 live per wave; full unroll for static indexing). Pass B: V staged
// (dbuf); P from E regs (no K reload, no QK MFMA, no exp); p_lds; PV.
// V-tile read swizzle upgraded to ^((row>>1)&3) (2-way = free); K-tile
// ^(ln&7) already conflict-free. Unshifted softmax.
__global__ __launch_bounds__(256) void attn_k(const u16* __restrict__ q,
                                              const u16* __restrict__ kk,
                                              const u16* __restrict__ vt,
                                              const float* __restrict__ lam,
                                              u16* __restrict__ ctx){
  const int h   = blockIdx.x >> 5;
  const int qt  = blockIdx.x & 31;
  const int qt0 = qt << 6;
  const int tid = threadIdx.x;
  const int w = tid >> 6, lane = tid & 63;
  const int quad = lane >> 4, ln = lane & 15;
  const int kvh = h >> 2;
  const float lam_h = lam[h];
  const float scale = 0.125f;   // 1/sqrt(64)
  const int qbw = qt0 + (w << 4);           // this wave's 16 q rows

  __shared__ __align__(16) u16 Ks[2][32 * 128];   // 16 KB
  __shared__ __align__(16) u16 Vs[2][128 * 32];   // 16 KB
  __shared__ __align__(16) u16 p_lds[4][2][16][40];

  s8b qf[4];   // A-layout: m = ln, k-slot (quad, s)
  {
    const u16* qrow = q + (size_t)(qbw + ln) * 2048 + h * 128 + quad * 8;
    #pragma unroll
    for (int s = 0; s < 4; ++s) qf[s] = *(const s8b*)(qrow + s * 32);
  }

  const int tlo = (qt0 > 511) ? ((qt0 - 511) >> 5) : 0;
  const int thi = ((qt0 + 63) >> 5) + 1;    // block-union tiles; thi-tlo <= 18

#define STAGE_K(buf, t) {                                                         \
    const int kc = (t) << 5;                                                      \
    _Pragma("unroll")                                                             \
    for (int i_ = 0; i_ < 2; ++i_){                                               \
      const int slot = tid + i_ * 256;                                            \
      const int row_ = slot >> 4, c16_ = slot & 15;                               \
      const u16* src_ = kk + (size_t)(kc + row_) * 512 + kvh * 128                \
                        + ((c16_ ^ (row_ & 7)) << 3);                             \
      gload16(src_, &Ks[buf][slot * 8]);                                          \
    } }
#define STAGE_V(buf, t) {                                                         \
    const int kc = (t) << 5;                                                      \
    _Pragma("unroll")                                                             \
    for (int i_ = 0; i_ < 2; ++i_){                                               \
      const int slot = tid + i_ * 256;                                            \
      const int row_ = slot >> 2, c16_ = slot & 3;                                \
      const u16* src_ = vt + (size_t)(kvh * 128 + row_) * 2048 + kc               \
                        + ((c16_ ^ ((row_ >> 1) & 3)) << 3);                      \
      gload16(src_, &Vs[buf][slot * 8]);                                          \
    } }

  // ---- Pass A: K staged; QK^T + exp ONCE; E -> f16 regs; l sums ----
  h8 eh[18], eh2[18];    // static-indexed only (full unroll)
  float l1[4] = {0.f,0.f,0.f,0.f}, l2[4] = {0.f,0.f,0.f,0.f};

  STAGE_K(0, tlo);
  asm volatile("s_waitcnt vmcnt(0)" ::: "memory");
  __builtin_amdgcn_s_barrier();
  #pragma unroll
  for (int tt = 0; tt < 18; ++tt){
    const int t = tlo + tt;
    if (t >= thi) continue;                  // block-uniform
    const int cur = tt & 1;
    if (t + 1 < thi){
      STAGE_K(cur ^ 1, t + 1);
      asm volatile("s_waitcnt vmcnt(2)" ::: "memory");
    } else {
      asm volatile("s_waitcnt vmcnt(0)" ::: "memory");
    }
    __builtin_amdgcn_s_barrier();
    const int kcol0 = t << 5;
    if (kcol0 <= qbw + 15 && kcol0 + 31 >= qbw - 511){   // wave-uniform
      #pragma unroll
      for (int sub = 0; sub < 2; ++sub){
        const int krow = (sub*16 + ln) * 128;
        s8b kf0 = *(const s8b*)&Ks[cur][krow + (((quad +  0) ^ (ln & 7)) << 3)];
        s8b kf1 = *(const s8b*)&Ks[cur][krow + (((quad +  4) ^ (ln & 7)) << 3)];
        s8b kf2 = *(const s8b*)&Ks[cur][krow + (((quad +  8) ^ (ln & 7)) << 3)];
        s8b kf3 = *(const s8b*)&Ks[cur][krow + (((quad + 12) ^ (ln & 7)) << 3)];
        f4 z = {0.f,0.f,0.f,0.f};
        f4 s1 = mfma16(qf[1], kf1, mfma16(qf[0], kf0, z));
        f4 s2 = mfma16(qf[3], kf3, mfma16(qf[2], kf2, z));
        const int col = kcol0 + sub*16 + ln;
        h8 ev;
        #pragma unroll
        for (int r = 0; r < 4; ++r){
          const int row = qbw + quad*4 + r;
          const bool ok = (col <= row) && (col > row - 512);
          const float a = ok ? __expf(s1[r] * scale) * 0.0625f : 0.f;
          const float b = ok ? __expf(s2[r] * scale) * 0.0625f : 0.f;
          l1[r] += a; l2[r] += b;
          ev[2*r]   = (_Float16)a;
          ev[2*r+1] = (_Float16)b;
        }
        if (sub == 0) eh[tt] = ev; else eh2[tt] = ev;
      }
    }
    asm volatile("s_waitcnt lgkmcnt(0)" ::: "memory");
    __builtin_amdgcn_s_barrier();
  }
  #pragma unroll
  for (int r = 0; r < 4; ++r){
    #pragma unroll
    for (int off = 1; off < 16; off <<= 1){
      l1[r] += __shfl_xor(l1[r], off, 16);
      l2[r] += __shfl_xor(l2[r], off, 16);
    }
  }
  float il1[4], il2[4];
  #pragma unroll
  for (int r = 0; r < 4; ++r){ il1[r] = 1.f / l1[r]; il2[r] = 1.f / l2[r]; }

  // ---- Pass B: V staged; P from E regs; p_lds; PV ----
  f4 acc[8];
  #pragma unroll
  for (int dt = 0; dt < 8; ++dt){ f4 z = {0.f,0.f,0.f,0.f}; acc[dt] = z; }
  float den[4] = {0.f,0.f,0.f,0.f};

  STAGE_V(0, tlo);
  asm volatile("s_waitcnt vmcnt(0)" ::: "memory");
  __builtin_amdgcn_s_barrier();
  #pragma unroll
  for (int tt = 0; tt < 18; ++tt){
    const int t = tlo + tt;
    if (t >= thi) continue;                  // block-uniform
    const int cur = tt & 1;
    if (t + 1 < thi){
      STAGE_V(cur ^ 1, t + 1);
      asm volatile("s_waitcnt vmcnt(2)" ::: "memory");
    } else {
      asm volatile("s_waitcnt vmcnt(0)" ::: "memory");
    }
    __builtin_amdgcn_s_barrier();
    const int kcol0 = t << 5;
    if (kcol0 <= qbw + 15 && kcol0 + 31 >= qbw - 511){   // wave-uniform
      #pragma unroll
      for (int sub = 0; sub < 2; ++sub){
        const h8 ev = (sub == 0) ? eh[tt] : eh2[tt];
        #pragma unroll
        for (int r = 0; r < 4; ++r){
          const float a = (float)ev[2*r];
          const float b = (float)ev[2*r+1];
          const float pd = fmaxf(a * il1[r] - lam_h * (b * il2[r]), 0.f);
          den[r] += pd;
          p_lds[w][cur][quad*4 + r][sub*16 + ln] = f2b(pd);
        }
      }
      // per-wave LDS slice: within-wave RAW handled by lgkmcnt.
      s8b pf = *(const s8b*)&p_lds[w][cur][ln][quad * 8];
      #pragma unroll
      for (int dt = 0; dt < 8; ++dt){
        s8b vf = *(const s8b*)&Vs[cur][(dt*16 + ln)*32 + (((quad) ^ ((ln >> 1) & 3)) << 3)];
        acc[dt] = mfma16(pf, vf, acc[dt]);
      }
    }
    asm volatile("s_waitcnt lgkmcnt(0)" ::: "memory");
    __builtin_amdgcn_s_barrier();
  }

  #pragma unroll
  for (int r = 0; r < 4; ++r)
    #pragma unroll
    for (int off = 1; off < 16; off <<= 1)
      den[r] += __shfl_xor(den[r], off, 16);
  #pragma unroll
  for (int r = 0; r < 4; ++r){
    const float dn = 1.f / (den[r] + 1e-6f);
    const int row = qbw + quad*4 + r;
    u16* orow = ctx + (size_t)row * 2048 + h * 128 + ln;
    #pragma unroll
    for (int dt = 0; dt < 8; ++dt)
      orow[dt * 16] = f2b(acc[dt][r] * dn);
  }
#undef STAGE_K
#undef STAGE_V
}

// ------------- launch ------------------------------------------------------
extern "C" void kernel_launch(void* const* d_in, const int* in_sizes, int n_in,
                              void* d_out, int out_size, void* d_ws, size_t ws_size,
                              hipStream_t stream){
  (void)in_sizes; (void)n_in; (void)out_size; (void)ws_size;
  const float* x   = (const float*)d_in[0];
  const float* Wq  = (const float*)d_in[1];
  const float* Wk  = (const float*)d_in[2];
  const float* Wv  = (const float*)d_in[3];
  const float* Wo  = (const float*)d_in[4];
  const float* lam = (const float*)d_in[5];
  char* ws = (char*)d_ws;
  // ws (<=17.1 MB of the 20 MB budget):
  //   WT  [0, 12.6)  fused [WqT;WkT;WvT] = 3072x2048 bf16
  //   kb  [13, 15)   roped k
  //   vtb [15, 17)   v^T
  //   ctx [0, 8)     reuse of WT after fused gemm
  //   WoT [8, 16)    reuse after attn (kb/vtb dead)
  u16* WT  = (u16*)(ws);
  u16* kb  = (u16*)(ws + (size_t)(13u << 20));
  u16* vtb = (u16*)(ws + (size_t)(15u << 20));
  u16* ctx = WT;
  u16* WoT = (u16*)(ws + (size_t)( 8u << 20));
  // d_out (16 MB fp32): xb [0,8), qb [8,16). Both dead before the final gemm,
  // which reads only ctx/WoT (ws) and overwrites all of d_out.
  u16* xb  = (u16*)d_out;
  u16* qb  = (u16*)((char*)d_out + (size_t)(8u << 20));
  float* out = (float*)d_out;

  const dim3 tb(32, 8);
  convert_k<<<2048, 256, 0, stream>>>(x, xb, 2048 * 2048 / 8);
  // fused weight transpose: WT rows [0,2048)=WqT, [2048,2560)=WkT, [2560,3072)=WvT
  transpose3_k<<<dim3(96, 64), tb, 0, stream>>>(Wq, Wk, Wv, WT);
  // fused QKV projection: [q | k | v^T]
  gemm8<0><<<dim3(24, 16), 512, 0, stream>>>(xb, WT, qb, kb, vtb, nullptr, 2048, 2048);
  // fused RoPE (q and k)
  rope2_k<<<2048, 256, 0, stream>>>(qb, kb);
  // diff-attention -> ctx (64 q-rows/block, single-QK + E-in-regs)
  attn_k<<<512, 256, 0, stream>>>(qb, kb, vtb, lam, ctx);
  // out = ctx @ Wo
  transpose_k<<<dim3(64, 64), tb, 0, stream>>>(Wo, WoT, 2048, 2048);
  gemm8<1><<<dim3(16, 16), 512, 0, stream>>>(ctx, WoT, nullptr, nullptr, nullptr, out, 2048, 2048);
}